// Round 17
// baseline (80.736 us; speedup 1.0000x reference)
//
#include <hip/hip_runtime.h>

#define NB 512
#define NC 512
#define HD 128
typedef float2 f2;
typedef float4 f4;

// 2-row k-split matmul (4 accs/thread): thread = (cg: f2 out col, slot: k-8th)
#define ACC4(SRC, WP, KQ) { const f2* W2_ = (const f2*)(WP); \
  _Pragma("unroll 8") for (int kk_ = 0; kk_ < (KQ); ++kk_) { \
    int k_ = slot * (KQ) + kk_; \
    f2 w_ = W2_[k_ * 64 + cg]; \
    float s0_ = SRC[0][k_], s1_ = SRC[1][k_]; \
    a0 = fmaf(s0_, w_.x, a0); a1 = fmaf(s0_, w_.y, a1); \
    a2 = fmaf(s1_, w_.x, a2); a3 = fmaf(s1_, w_.y, a3); } }
#define ZACC4() { a0=a1=a2=a3=0.f; }
#define WRPART2() { *(f2*)&part2[slot][0][c0] = make_float2(a0, a1); \
  *(f2*)&part2[slot][1][c0] = make_float2(a2, a3); }
#define PSUM2(r_, cc_) (part2[0][r_][cc_] + part2[1][r_][cc_] + part2[2][r_][cc_] + \
                        part2[3][r_][cc_] + part2[4][r_][cc_] + part2[5][r_][cc_] + \
                        part2[6][r_][cc_] + part2[7][r_][cc_])

// 1-row variant (2 accs/thread)
#define ACC2(SRC, WP, KQ) { const f2* W2_ = (const f2*)(WP); \
  _Pragma("unroll 8") for (int kk_ = 0; kk_ < (KQ); ++kk_) { \
    int k_ = slot * (KQ) + kk_; \
    f2 w_ = W2_[k_ * 64 + cg]; \
    float s0_ = (SRC)[k_]; \
    a0 = fmaf(s0_, w_.x, a0); a1 = fmaf(s0_, w_.y, a1); } }
#define PSUM1(cc_) (part1[0][cc_] + part1[1][cc_] + part1[2][cc_] + part1[3][cc_] + \
                    part1[4][cc_] + part1[5][cc_] + part1[6][cc_] + part1[7][cc_])

// ---------------------------------------------------------------------------
// k_pre: 512 blocks x 512 thr — 2 blocks/CU.  (byte-identical to R16)
// ---------------------------------------------------------------------------
__global__ __launch_bounds__(512) void k_pre(
    const float* __restrict__ probs, const float* __restrict__ npw,
    const float* __restrict__ npb, const float* __restrict__ ew1,
    const float* __restrict__ eb1, float* __restrict__ x0,
    float* __restrict__ u, float* __restrict__ v, int* __restrict__ idx) {
  __shared__ float srt[NC];          // 2 KB
  __shared__ float As[2][NC];        // 4 KB
  __shared__ float xs[2][HD];        // 1 KB
  __shared__ float part2[8][2][HD];  // 8 KB
  const int tid = threadIdx.x, b = blockIdx.x;
  const int cg = tid & 63, slot = tid >> 6;
  const int c0 = 2 * cg;
  float a0, a1, a2, a3;

  // ---- sort row b: 512 threads, 1 element each ----
  {
    srt[tid] = probs[b * NC + tid];
    __syncthreads();
    const float myv = srt[tid];
    int rank = 0;
#pragma unroll 8
    for (int j4 = 0; j4 < 128; ++j4) {
      f4 sv = ((const f4*)srt)[j4];
      int j = 4 * j4;
      rank += (sv.x > myv) || (sv.x == myv && (j + 0) < tid);
      rank += (sv.y > myv) || (sv.y == myv && (j + 1) < tid);
      rank += (sv.z > myv) || (sv.z == myv && (j + 2) < tid);
      rank += (sv.w > myv) || (sv.w == myv && (j + 3) < tid);
    }
    idx[b * NC + rank] = tid;
  }

  if (b < 256) {                     // ---- bird: rows 2b, 2b+1 ----
    const int r0 = 2 * b;
    ((f2*)As)[tid] = ((const f2*)(probs + r0 * NC))[tid];
    __syncthreads();
    ZACC4(); ACC4(As, npw, 64);      // k=512, 64 per slot
    WRPART2();
    __syncthreads();
    if (tid < 256) { int r = tid >> 7, cc = tid & 127;
      float val = PSUM2(r, cc) + npb[cc];
      xs[r][cc] = val;
      x0[(r0 + r) * HD + cc] = val; }
    __syncthreads();
    ZACC4(); ACC4(xs, ew1, 16);      // u = xs @ ew1_top + eb1
    WRPART2();
    __syncthreads();
    if (tid < 256) { int r = tid >> 7, cc = tid & 127;
      u[(r0 + r) * HD + cc] = PSUM2(r, cc) + eb1[cc]; }
  } else {                           // ---- color: rows 2i, 2i+1 ----
    const int cr0 = 2 * (b - 256);
    __syncthreads();                 // srt reuse barrier symmetry
    if (tid < 256) { int r = tid >> 7, cc = tid & 127;
      float val = npw[(cr0 + r) * HD + cc] + npb[cc];
      xs[r][cc] = val;
      x0[(NB + cr0 + r) * HD + cc] = val; }
    __syncthreads();
    ZACC4(); ACC4(xs, ew1 + HD * HD, 16);   // v = xs @ ew1_bottom
    WRPART2();
    __syncthreads();
    if (tid < 256) { int r = tid >> 7, cc = tid & 127;
      v[(cr0 + r) * HD + cc] = PSUM2(r, cc); }
  }
}

// ---------------------------------------------------------------------------
// k_RSlayer: CHANGED — 512 blocks x 2 node rows; 2 blocks/CU. Same proven
// 2-row structure as k_pre/k_last (R13/R16 transform). Block b: bird if
// b<256 (node rows 2b,2b+1), color otherwise. RS never leaves LDS.
// ---------------------------------------------------------------------------
__global__ __launch_bounds__(512) void k_RSlayer(
    const float* __restrict__ xin, const float* __restrict__ uin,
    const float* __restrict__ vin,
    const float* __restrict__ ew2l, const float* __restrict__ eb2l,
    const float* __restrict__ nw1l, const float* __restrict__ nb1l,
    const float* __restrict__ nw2l, const float* __restrict__ nb2l,
    const float* __restrict__ ew1n, const float* __restrict__ eb1n,
    float* __restrict__ xout, float* __restrict__ uout, float* __restrict__ vout) {
  __shared__ float rsp[32][HD];      // 16 KB: 16 j-groups x 2 rows
  __shared__ float xa[2][HD], rs[2][HD], ag[2][HD], h1[2][HD], xo[2][HD];
  __shared__ float part2[8][2][HD];  // 8 KB
  const int tid = threadIdx.x, b = blockIdx.x;   // 0..511
  const int cg = tid & 63, slot = tid >> 6;
  const int c0 = 2 * cg;
  const int nr0 = b * 2;             // node row base
  const bool bird = b < 256;
  const int r0s = (b & 255) * 2;     // row base within side
  float a0, a1, a2, a3;

  if (tid < 128) ((f2*)xa)[tid] = ((const f2*)(xin + nr0 * HD))[tid];

  // ---- RS phase: 16 j-groups; each f4 of `other` feeds both rows ----
  {
    const float* mine  = bird ? uin : vin;
    const float* other = bird ? vin : uin;
    const int s16 = tid >> 5, cg32 = tid & 31;
    f4 b0 = *(const f4*)&mine[(r0s + 0) * HD + 4 * cg32];
    f4 b1 = *(const f4*)&mine[(r0s + 1) * HD + 4 * cg32];
    const f4* O4 = (const f4*)other;
    f4 c0v = make_float4(0.f, 0.f, 0.f, 0.f);
    f4 c1v = make_float4(0.f, 0.f, 0.f, 0.f);
#pragma unroll 8
    for (int j = s16 * 32; j < s16 * 32 + 32; ++j) {
      f4 o = O4[j * 32 + cg32];
      c0v.x += fmaxf(b0.x + o.x, 0.f); c0v.y += fmaxf(b0.y + o.y, 0.f);
      c0v.z += fmaxf(b0.z + o.z, 0.f); c0v.w += fmaxf(b0.w + o.w, 0.f);
      c1v.x += fmaxf(b1.x + o.x, 0.f); c1v.y += fmaxf(b1.y + o.y, 0.f);
      c1v.z += fmaxf(b1.z + o.z, 0.f); c1v.w += fmaxf(b1.w + o.w, 0.f);
    }
    *(f4*)&rsp[2 * s16 + 0][4 * cg32] = c0v;
    *(f4*)&rsp[2 * s16 + 1][4 * cg32] = c1v;
  }
  __syncthreads();
  if (tid < 256) { int r = tid >> 7, cc = tid & 127;
    float s = 0.f;
#pragma unroll
    for (int q = 0; q < 16; ++q) s += rsp[2 * q + r][cc];
    rs[r][cc] = s; }
  __syncthreads();

  ZACC4(); ACC4(rs, ew2l, 16);                   // phase 1: aggr
  WRPART2();
  __syncthreads();
  if (tid < 256) { int r = tid >> 7, cc = tid & 127;
    ag[r][cc] = PSUM2(r, cc) + 512.f * eb2l[cc]; }
  __syncthreads();

  ZACC4();                                       // phase 2: node MLP layer 1
  ACC4(xa, nw1l, 16);
  ACC4(ag, nw1l + HD * HD, 16);
  WRPART2();
  __syncthreads();
  if (tid < 256) { int r = tid >> 7, cc = tid & 127;
    h1[r][cc] = fmaxf(PSUM2(r, cc) + nb1l[cc], 0.f); }
  __syncthreads();

  ZACC4(); ACC4(h1, nw2l, 16);                   // phase 3: node MLP layer 2
  WRPART2();
  __syncthreads();
  if (tid < 256) { int r = tid >> 7, cc = tid & 127;
    float val = PSUM2(r, cc) + nb2l[cc];
    xo[r][cc] = val;
    xout[(nr0 + r) * HD + cc] = val; }
  __syncthreads();

  ZACC4(); ACC4(xo, (bird ? ew1n : ew1n + HD * HD), 16);  // phase 4: next u/v
  WRPART2();
  __syncthreads();
  if (tid < 256) { int r = tid >> 7, cc = tid & 127;
    float val = PSUM2(r, cc) + (bird ? eb1n[cc] : 0.f);
    if (bird) uout[(r0s + r) * HD + cc] = val;
    else      vout[(r0s + r) * HD + cc] = val; }
}

// ---------------------------------------------------------------------------
// k_last: 512 blocks x 1 bird row; 2 blocks/CU.  (byte-identical to R16)
// ---------------------------------------------------------------------------
__global__ __launch_bounds__(512) void k_last(
    const float* __restrict__ xin, const float* __restrict__ uin,
    const float* __restrict__ vin,
    const float* __restrict__ ew2l, const float* __restrict__ eb2l,
    const float* __restrict__ nw1l, const float* __restrict__ nb1l,
    const float* __restrict__ nw2l, const float* __restrict__ nb2l,
    const float* __restrict__ cpw, const float* __restrict__ cpb,
    const float* __restrict__ probs, const int* __restrict__ idx,
    float* __restrict__ out) {
  __shared__ float rsp[16][HD];      // 8 KB: 16 j-groups x 1 row
  __shared__ float xa[HD], rs[HD], ag[HD], h1[HD], xo[HD];   // 2.5 KB
  __shared__ float part1[8][HD];     // 4 KB
  __shared__ float comb[NC];         // 2 KB
  const int tid = threadIdx.x, b = blockIdx.x;   // b = bird row, 0..511
  const int cg = tid & 63, slot = tid >> 6;
  const int c0 = 2 * cg;
  float a0, a1;

  if (tid < 64) ((f2*)xa)[tid] = ((const f2*)(xin + b * HD))[tid];

  {  // ---- R phase over v: 16 j-groups x 32 lanes; each lane one f4 col ----
    const int s16 = tid >> 5, cg32 = tid & 31;
    f4 b0 = *(const f4*)&uin[b * HD + 4 * cg32];
    const f4* O4 = (const f4*)vin;
    f4 acc = make_float4(0.f, 0.f, 0.f, 0.f);
#pragma unroll 8
    for (int j = s16 * 32; j < s16 * 32 + 32; ++j) {
      f4 o = O4[j * 32 + cg32];
      acc.x += fmaxf(b0.x + o.x, 0.f);
      acc.y += fmaxf(b0.y + o.y, 0.f);
      acc.z += fmaxf(b0.z + o.z, 0.f);
      acc.w += fmaxf(b0.w + o.w, 0.f);
    }
    *(f4*)&rsp[s16][4 * cg32] = acc;
  }
  __syncthreads();
  if (tid < 128) {
    float s = 0.f;
#pragma unroll
    for (int q = 0; q < 16; ++q) s += rsp[q][tid];
    rs[tid] = s;
  }
  __syncthreads();

  a0 = a1 = 0.f; ACC2(rs, ew2l, 16);
  *(f2*)&part1[slot][c0] = make_float2(a0, a1);
  __syncthreads();
  if (tid < 128) ag[tid] = PSUM1(tid) + 512.f * eb2l[tid];
  __syncthreads();

  a0 = a1 = 0.f;
  ACC2(xa, nw1l, 16);
  ACC2(ag, nw1l + HD * HD, 16);
  *(f2*)&part1[slot][c0] = make_float2(a0, a1);
  __syncthreads();
  if (tid < 128) h1[tid] = fmaxf(PSUM1(tid) + nb1l[tid], 0.f);
  __syncthreads();

  a0 = a1 = 0.f; ACC2(h1, nw2l, 16);
  *(f2*)&part1[slot][c0] = make_float2(a0, a1);
  __syncthreads();
  if (tid < 128) xo[tid] = PSUM1(tid) + nb2l[tid];
  __syncthreads();

  // ---- gnn score + combine: thread = one output column ----
  {
    float s0 = cpb[tid];
#pragma unroll 8
    for (int k = 0; k < HD; ++k)
      s0 = fmaf(xo[k], cpw[k * NC + tid], s0);
    comb[tid] = s0 * probs[b * NC + tid];
  }
  __syncthreads();
  {
    int cc = idx[b * NC + tid];
    out[b * NC + tid] = 1.f - comb[cc];
  }
}

extern "C" void kernel_launch(void* const* d_in, const int* in_sizes, int n_in,
                              void* d_out, int out_size, void* d_ws, size_t ws_size,
                              hipStream_t stream) {
  const float* probs = (const float*)d_in[0];
  const float* npw   = (const float*)d_in[1];
  const float* npb   = (const float*)d_in[2];
  const float* ew1   = (const float*)d_in[3];
  const float* eb1   = (const float*)d_in[4];
  const float* ew2   = (const float*)d_in[5];
  const float* eb2   = (const float*)d_in[6];
  const float* nw1   = (const float*)d_in[7];
  const float* nb1   = (const float*)d_in[8];
  const float* nw2   = (const float*)d_in[9];
  const float* nb2   = (const float*)d_in[10];
  const float* cpw   = (const float*)d_in[11];
  const float* cpb   = (const float*)d_in[12];
  float* out = (float*)d_out;

  float* x0 = (float*)d_ws;          // 1024*128
  float* x1 = x0 + 1024 * HD;
  float* ua = x1 + 1024 * HD;        // 512*128 each
  float* va = ua + NB * HD;
  float* ub = va + NC * HD;
  float* vb = ub + NB * HD;
  int*  idx = (int*)(vb + NC * HD);  // 512*512

  k_pre    <<<512, 512, 0, stream>>>(probs, npw, npb, ew1, eb1, x0, ua, va, idx);
  // layer 0: x0 -> x1, (ua,va) -> (ub,vb)
  k_RSlayer<<<512, 512, 0, stream>>>(x0, ua, va, ew2, eb2, nw1, nb1, nw2, nb2,
                                     ew1 + 32768, eb1 + HD, x1, ub, vb);
  // layer 1: x1 -> x0, (ub,vb) -> (ua,va)
  k_RSlayer<<<512, 512, 0, stream>>>(x1, ub, vb, ew2 + 16384, eb2 + HD,
                                     nw1 + 32768, nb1 + HD, nw2 + 16384, nb2 + HD,
                                     ew1 + 65536, eb1 + 2 * HD, x0, ua, va);
  // layer 2 (bird only), 512 blocks x 1 row, fused through to d_out
  k_last   <<<512, 512, 0, stream>>>(x0, ua, va, ew2 + 32768, eb2 + 2 * HD,
                                     nw1 + 65536, nb1 + 2 * HD,
                                     nw2 + 32768, nb2 + 2 * HD,
                                     cpw, cpb, probs, idx, out);
}

// Round 18
// 77.588 us; speedup vs baseline: 1.0406x; 1.0406x over previous
//
#include <hip/hip_runtime.h>

#define NB 512
#define NC 512
#define HD 128
typedef float2 f2;
typedef float4 f4;

// 8-slot k-split matmul, 4-row variant (8 accs/thread)
#define ACC8(SRC, WP, KQ) { const f2* W2_ = (const f2*)(WP); \
  _Pragma("unroll 8") for (int kk_ = 0; kk_ < (KQ); ++kk_) { \
    int k_ = slot * (KQ) + kk_; \
    f2 w_ = W2_[k_ * 64 + cg]; \
    float s0_ = SRC[0][k_], s1_ = SRC[1][k_], s2_ = SRC[2][k_], s3_ = SRC[3][k_]; \
    a0 = fmaf(s0_, w_.x, a0); a1 = fmaf(s0_, w_.y, a1); \
    a2 = fmaf(s1_, w_.x, a2); a3 = fmaf(s1_, w_.y, a3); \
    a4 = fmaf(s2_, w_.x, a4); a5 = fmaf(s2_, w_.y, a5); \
    a6 = fmaf(s3_, w_.x, a6); a7 = fmaf(s3_, w_.y, a7); } }
#define ZACC() { a0=a1=a2=a3=a4=a5=a6=a7=0.f; }
#define WRPART() { *(f2*)&part[slot][0][c0] = make_float2(a0, a1); \
  *(f2*)&part[slot][1][c0] = make_float2(a2, a3); \
  *(f2*)&part[slot][2][c0] = make_float2(a4, a5); \
  *(f2*)&part[slot][3][c0] = make_float2(a6, a7); }
#define PSUM(r_, cc_) (part[0][r_][cc_] + part[1][r_][cc_] + part[2][r_][cc_] + \
                       part[3][r_][cc_] + part[4][r_][cc_] + part[5][r_][cc_] + \
                       part[6][r_][cc_] + part[7][r_][cc_])

// 2-row variant (4 accs/thread)
#define ACC4(SRC, WP, KQ) { const f2* W2_ = (const f2*)(WP); \
  _Pragma("unroll 8") for (int kk_ = 0; kk_ < (KQ); ++kk_) { \
    int k_ = slot * (KQ) + kk_; \
    f2 w_ = W2_[k_ * 64 + cg]; \
    float s0_ = SRC[0][k_], s1_ = SRC[1][k_]; \
    a0 = fmaf(s0_, w_.x, a0); a1 = fmaf(s0_, w_.y, a1); \
    a2 = fmaf(s1_, w_.x, a2); a3 = fmaf(s1_, w_.y, a3); } }
#define ZACC4() { a0=a1=a2=a3=0.f; }
#define WRPART2() { *(f2*)&part2[slot][0][c0] = make_float2(a0, a1); \
  *(f2*)&part2[slot][1][c0] = make_float2(a2, a3); }
#define PSUM2(r_, cc_) (part2[0][r_][cc_] + part2[1][r_][cc_] + part2[2][r_][cc_] + \
                        part2[3][r_][cc_] + part2[4][r_][cc_] + part2[5][r_][cc_] + \
                        part2[6][r_][cc_] + part2[7][r_][cc_])

// 1-row variant (2 accs/thread)
#define ACC2(SRC, WP, KQ) { const f2* W2_ = (const f2*)(WP); \
  _Pragma("unroll 8") for (int kk_ = 0; kk_ < (KQ); ++kk_) { \
    int k_ = slot * (KQ) + kk_; \
    f2 w_ = W2_[k_ * 64 + cg]; \
    float s0_ = (SRC)[k_]; \
    a0 = fmaf(s0_, w_.x, a0); a1 = fmaf(s0_, w_.y, a1); } }
#define PSUM1(cc_) (part1[0][cc_] + part1[1][cc_] + part1[2][cc_] + part1[3][cc_] + \
                    part1[4][cc_] + part1[5][cc_] + part1[6][cc_] + part1[7][cc_])

// ---------------------------------------------------------------------------
// k_pre: 512 blocks x 512 thr — 2 blocks/CU.
//  Every block sorts probs row b (stable-descending rank, lax.top_k order).
//  blocks 0-255 (bird, rows 2b,2b+1): x0 = probs@npw+b; u0 = x0@ew1_top+eb1.
//  blocks 256-511 (color, rows 2i,2i+1): x0 = npw_row+b; v0 = x0@ew1_bot.
// ---------------------------------------------------------------------------
__global__ __launch_bounds__(512) void k_pre(
    const float* __restrict__ probs, const float* __restrict__ npw,
    const float* __restrict__ npb, const float* __restrict__ ew1,
    const float* __restrict__ eb1, float* __restrict__ x0,
    float* __restrict__ u, float* __restrict__ v, int* __restrict__ idx) {
  __shared__ float srt[NC];          // 2 KB
  __shared__ float As[2][NC];        // 4 KB
  __shared__ float xs[2][HD];        // 1 KB
  __shared__ float part2[8][2][HD];  // 8 KB
  const int tid = threadIdx.x, b = blockIdx.x;
  const int cg = tid & 63, slot = tid >> 6;
  const int c0 = 2 * cg;
  float a0, a1, a2, a3;

  // ---- sort row b: 512 threads, 1 element each ----
  {
    srt[tid] = probs[b * NC + tid];
    __syncthreads();
    const float myv = srt[tid];
    int rank = 0;
#pragma unroll 8
    for (int j4 = 0; j4 < 128; ++j4) {
      f4 sv = ((const f4*)srt)[j4];
      int j = 4 * j4;
      rank += (sv.x > myv) || (sv.x == myv && (j + 0) < tid);
      rank += (sv.y > myv) || (sv.y == myv && (j + 1) < tid);
      rank += (sv.z > myv) || (sv.z == myv && (j + 2) < tid);
      rank += (sv.w > myv) || (sv.w == myv && (j + 3) < tid);
    }
    idx[b * NC + rank] = tid;
  }

  if (b < 256) {                     // ---- bird: rows 2b, 2b+1 ----
    const int r0 = 2 * b;
    ((f2*)As)[tid] = ((const f2*)(probs + r0 * NC))[tid];
    __syncthreads();
    ZACC4(); ACC4(As, npw, 64);      // k=512, 64 per slot
    WRPART2();
    __syncthreads();
    if (tid < 256) { int r = tid >> 7, cc = tid & 127;
      float val = PSUM2(r, cc) + npb[cc];
      xs[r][cc] = val;
      x0[(r0 + r) * HD + cc] = val; }
    __syncthreads();
    ZACC4(); ACC4(xs, ew1, 16);      // u = xs @ ew1_top + eb1
    WRPART2();
    __syncthreads();
    if (tid < 256) { int r = tid >> 7, cc = tid & 127;
      u[(r0 + r) * HD + cc] = PSUM2(r, cc) + eb1[cc]; }
  } else {                           // ---- color: rows 2i, 2i+1 ----
    const int cr0 = 2 * (b - 256);
    __syncthreads();                 // srt reuse barrier symmetry
    if (tid < 256) { int r = tid >> 7, cc = tid & 127;
      float val = npw[(cr0 + r) * HD + cc] + npb[cc];
      xs[r][cc] = val;
      x0[(NB + cr0 + r) * HD + cc] = val; }
    __syncthreads();
    ZACC4(); ACC4(xs, ew1 + HD * HD, 16);   // v = xs @ ew1_bottom
    WRPART2();
    __syncthreads();
    if (tid < 256) { int r = tid >> 7, cc = tid & 127;
      v[(cr0 + r) * HD + cc] = PSUM2(r, cc); }
  }
}

// ---------------------------------------------------------------------------
// k_RSlayer: fused relu-sum + layer. 256 blocks x 4 rows (byte-identical to
// R7/R12/R16 — frozen; both 2-blocks/CU variants regressed, R10/R11/R17)
// ---------------------------------------------------------------------------
__global__ __launch_bounds__(512) void k_RSlayer(
    const float* __restrict__ xin, const float* __restrict__ uin,
    const float* __restrict__ vin,
    const float* __restrict__ ew2l, const float* __restrict__ eb2l,
    const float* __restrict__ nw1l, const float* __restrict__ nb1l,
    const float* __restrict__ nw2l, const float* __restrict__ nb2l,
    const float* __restrict__ ew1n, const float* __restrict__ eb1n,
    float* __restrict__ xout, float* __restrict__ uout, float* __restrict__ vout) {
  __shared__ float rsp[16][HD];      // 8 KB RS partials
  __shared__ float xa[4][HD], rs[4][HD], ag[4][HD], h1[4][HD], xo[4][HD];
  __shared__ float part[8][4][HD];   // 16 KB
  const int tid = threadIdx.x, b = blockIdx.x;
  const int cg = tid & 63, slot = tid >> 6;
  const int c0 = 2 * cg;
  const int nr0 = b * 4;
  const bool bird = b < 128;
  const int r0s = (b & 127) * 4;
  float a0, a1, a2, a3, a4, a5, a6, a7;

  if (tid < 256) ((f2*)xa)[tid] = ((const f2*)(xin + nr0 * HD))[tid];

  // ---- RS phase: 16 slots = 4 rows x 4 j-quarters, f4 loads from L2 ----
  {
    const float* mine  = bird ? uin : vin;
    const float* other = bird ? vin : uin;
    const int s16 = tid >> 5, cg32 = tid & 31;
    const int row = s16 & 3, jq = s16 >> 2;
    f4 base = *(const f4*)&mine[(r0s + row) * HD + 4 * cg32];
    const f4* O4 = (const f4*)other;
    f4 acc = make_float4(0.f, 0.f, 0.f, 0.f);
#pragma unroll 8
    for (int j = jq * 128; j < jq * 128 + 128; ++j) {
      f4 o = O4[j * 32 + cg32];
      acc.x += fmaxf(base.x + o.x, 0.f);
      acc.y += fmaxf(base.y + o.y, 0.f);
      acc.z += fmaxf(base.z + o.z, 0.f);
      acc.w += fmaxf(base.w + o.w, 0.f);
    }
    *(f4*)&rsp[s16][4 * cg32] = acc;
  }
  __syncthreads();
  { int r = tid >> 7, cc = tid & 127;
    rs[r][cc] = rsp[r][cc] + rsp[4 + r][cc] + rsp[8 + r][cc] + rsp[12 + r][cc]; }
  __syncthreads();

  ZACC(); ACC8(rs, ew2l, 16);                    // phase 1: aggr
  WRPART();
  __syncthreads();
  { int r = tid >> 7, cc = tid & 127;
    ag[r][cc] = PSUM(r, cc) + 512.f * eb2l[cc]; }
  __syncthreads();

  ZACC();                                        // phase 2: node MLP layer 1
  ACC8(xa, nw1l, 16);
  ACC8(ag, nw1l + HD * HD, 16);
  WRPART();
  __syncthreads();
  { int r = tid >> 7, cc = tid & 127;
    h1[r][cc] = fmaxf(PSUM(r, cc) + nb1l[cc], 0.f); }
  __syncthreads();

  ZACC(); ACC8(h1, nw2l, 16);                    // phase 3: node MLP layer 2
  WRPART();
  __syncthreads();
  { int r = tid >> 7, cc = tid & 127;
    float val = PSUM(r, cc) + nb2l[cc];
    xo[r][cc] = val;
    xout[(nr0 + r) * HD + cc] = val; }
  __syncthreads();

  ZACC(); ACC8(xo, (bird ? ew1n : ew1n + HD * HD), 16);   // phase 4: next u/v
  WRPART();
  __syncthreads();
  { int r = tid >> 7, cc = tid & 127;
    float val = PSUM(r, cc) + (bird ? eb1n[cc] : 0.f);
    if (bird) uout[(nr0 + r) * HD + cc] = val;
    else      vout[(nr0 - NB + r) * HD + cc] = val; }
}

// ---------------------------------------------------------------------------
// k_last: 512 blocks x 1 bird row; 2 blocks/CU. R-sum + aggr + node MLP +
// gnn + combine + gather -> d_out.  (byte-identical to R16)
// ---------------------------------------------------------------------------
__global__ __launch_bounds__(512) void k_last(
    const float* __restrict__ xin, const float* __restrict__ uin,
    const float* __restrict__ vin,
    const float* __restrict__ ew2l, const float* __restrict__ eb2l,
    const float* __restrict__ nw1l, const float* __restrict__ nb1l,
    const float* __restrict__ nw2l, const float* __restrict__ nb2l,
    const float* __restrict__ cpw, const float* __restrict__ cpb,
    const float* __restrict__ probs, const int* __restrict__ idx,
    float* __restrict__ out) {
  __shared__ float rsp[16][HD];      // 8 KB: 16 j-groups x 1 row
  __shared__ float xa[HD], rs[HD], ag[HD], h1[HD], xo[HD];   // 2.5 KB
  __shared__ float part1[8][HD];     // 4 KB
  __shared__ float comb[NC];         // 2 KB
  const int tid = threadIdx.x, b = blockIdx.x;   // b = bird row, 0..511
  const int cg = tid & 63, slot = tid >> 6;
  const int c0 = 2 * cg;
  float a0, a1;

  if (tid < 64) ((f2*)xa)[tid] = ((const f2*)(xin + b * HD))[tid];

  {  // ---- R phase over v: 16 j-groups x 32 lanes; each lane one f4 col ----
    const int s16 = tid >> 5, cg32 = tid & 31;
    f4 b0 = *(const f4*)&uin[b * HD + 4 * cg32];
    const f4* O4 = (const f4*)vin;
    f4 acc = make_float4(0.f, 0.f, 0.f, 0.f);
#pragma unroll 8
    for (int j = s16 * 32; j < s16 * 32 + 32; ++j) {
      f4 o = O4[j * 32 + cg32];
      acc.x += fmaxf(b0.x + o.x, 0.f);
      acc.y += fmaxf(b0.y + o.y, 0.f);
      acc.z += fmaxf(b0.z + o.z, 0.f);
      acc.w += fmaxf(b0.w + o.w, 0.f);
    }
    *(f4*)&rsp[s16][4 * cg32] = acc;
  }
  __syncthreads();
  if (tid < 128) {
    float s = 0.f;
#pragma unroll
    for (int q = 0; q < 16; ++q) s += rsp[q][tid];
    rs[tid] = s;
  }
  __syncthreads();

  a0 = a1 = 0.f; ACC2(rs, ew2l, 16);
  *(f2*)&part1[slot][c0] = make_float2(a0, a1);
  __syncthreads();
  if (tid < 128) ag[tid] = PSUM1(tid) + 512.f * eb2l[tid];
  __syncthreads();

  a0 = a1 = 0.f;
  ACC2(xa, nw1l, 16);
  ACC2(ag, nw1l + HD * HD, 16);
  *(f2*)&part1[slot][c0] = make_float2(a0, a1);
  __syncthreads();
  if (tid < 128) h1[tid] = fmaxf(PSUM1(tid) + nb1l[tid], 0.f);
  __syncthreads();

  a0 = a1 = 0.f; ACC2(h1, nw2l, 16);
  *(f2*)&part1[slot][c0] = make_float2(a0, a1);
  __syncthreads();
  if (tid < 128) xo[tid] = PSUM1(tid) + nb2l[tid];
  __syncthreads();

  // ---- gnn score + combine: thread = one output column ----
  {
    float s0 = cpb[tid];
#pragma unroll 8
    for (int k = 0; k < HD; ++k)
      s0 = fmaf(xo[k], cpw[k * NC + tid], s0);
    comb[tid] = s0 * probs[b * NC + tid];
  }
  __syncthreads();
  {
    int cc = idx[b * NC + tid];
    out[b * NC + tid] = 1.f - comb[cc];
  }
}

extern "C" void kernel_launch(void* const* d_in, const int* in_sizes, int n_in,
                              void* d_out, int out_size, void* d_ws, size_t ws_size,
                              hipStream_t stream) {
  const float* probs = (const float*)d_in[0];
  const float* npw   = (const float*)d_in[1];
  const float* npb   = (const float*)d_in[2];
  const float* ew1   = (const float*)d_in[3];
  const float* eb1   = (const float*)d_in[4];
  const float* ew2   = (const float*)d_in[5];
  const float* eb2   = (const float*)d_in[6];
  const float* nw1   = (const float*)d_in[7];
  const float* nb1   = (const float*)d_in[8];
  const float* nw2   = (const float*)d_in[9];
  const float* nb2   = (const float*)d_in[10];
  const float* cpw   = (const float*)d_in[11];
  const float* cpb   = (const float*)d_in[12];
  float* out = (float*)d_out;

  float* x0 = (float*)d_ws;          // 1024*128
  float* x1 = x0 + 1024 * HD;
  float* ua = x1 + 1024 * HD;        // 512*128 each
  float* va = ua + NB * HD;
  float* ub = va + NC * HD;
  float* vb = ub + NB * HD;
  int*  idx = (int*)(vb + NC * HD);  // 512*512

  k_pre    <<<512, 512, 0, stream>>>(probs, npw, npb, ew1, eb1, x0, ua, va, idx);
  // layer 0: x0 -> x1, (ua,va) -> (ub,vb)
  k_RSlayer<<<256, 512, 0, stream>>>(x0, ua, va, ew2, eb2, nw1, nb1, nw2, nb2,
                                     ew1 + 32768, eb1 + HD, x1, ub, vb);
  // layer 1: x1 -> x0, (ub,vb) -> (ua,va)
  k_RSlayer<<<256, 512, 0, stream>>>(x1, ub, vb, ew2 + 16384, eb2 + HD,
                                     nw1 + 32768, nb1 + HD, nw2 + 16384, nb2 + HD,
                                     ew1 + 65536, eb1 + 2 * HD, x0, ua, va);
  // layer 2 (bird only), 512 blocks x 1 row, fused through to d_out
  k_last   <<<512, 512, 0, stream>>>(x0, ua, va, ew2 + 32768, eb2 + 2 * HD,
                                     nw1 + 65536, nb1 + 2 * HD,
                                     nw2 + 32768, nb2 + 2 * HD,
                                     cpw, cpb, probs, idx, out);
}